// Round 1
// baseline (15746.129 us; speedup 1.0000x reference)
//
#include <hip/hip_runtime.h>
#include <cstddef>

// ---------------- workspace layout (float offsets) ----------------
static constexpr size_t BIGA   = 0;              // 4194304  stem out / c1 out
static constexpr size_t BIGB   = 4194304;        // 2097152  pool / c2 / T
static constexpr size_t BIGC   = 6291456;        // 1048576  c3 out
static constexpr size_t FEATO  = 7340032;        // 2097152  feat [2048][1024]
static constexpr size_t FEATT  = 9437184;        // 2097152  featT [1024][2048]
static constexpr size_t OBJO   = 11534336;       // 12288
static constexpr size_t REGO   = 11546624;       // 49152
static constexpr size_t BOXO   = 11595776;       // 49152
static constexpr size_t KEYO   = 11644928;       // 24576 (u64 x 12288)
static constexpr size_t CANDO  = 11669504;       // 4000
static constexpr size_t SUPO   = 11673504;       // 32000 (u64 x 16000)
static constexpr size_t PROPO  = 11705504;       // 1024
static constexpr size_t POOLO  = 11706528;       // 25690112 [256][49][2048]
static constexpr size_t PARTO  = POOLO;          // alias: conv k-split partials (<=8388608), dead before pooled
static constexpr size_t FC1PO  = 37396640;       // 4194304 [16][256][1024]
static constexpr size_t H1O    = 41590944;       // 262144
static constexpr size_t H2O    = 41853088;       // 262144
// total 42115232 floats = 161 MiB

// ---------------- stem: 7x7 s2 pad3, Cin=3 -> [64,256,256], relu ----------------
__launch_bounds__(256)
__global__ void stem_k(const float* __restrict__ img, const float* __restrict__ w,
                       float* __restrict__ out) {
  __shared__ float ins[3 * 37 * 40];
  __shared__ float wsm[160];
  int bx = blockIdx.x;
  int oc = bx >> 8;
  int t = bx & 255;
  int ty = t >> 4, tx = t & 15;
  int tid = threadIdx.x;
  for (int idx = tid; idx < 147; idx += 256) wsm[idx] = w[oc * 147 + idx];
  int iy0 = ty * 32 - 3, ix0 = tx * 32 - 3;
  for (int idx = tid; idx < 3 * 37 * 40; idx += 256) {
    int c = idx / 1480;
    int r = idx - c * 1480;
    int iy = r / 40, ix = r - iy * 40;
    int gy = iy0 + iy, gx = ix0 + ix;
    float v = 0.f;
    if (ix < 37 && (unsigned)gy < 512u && (unsigned)gx < 512u)
      v = img[(size_t)c * 262144 + (size_t)gy * 512 + gx];
    ins[idx] = v;
  }
  __syncthreads();
  int row = tid >> 4, col = tid & 15;
  float acc = 0.f;
#pragma unroll
  for (int c = 0; c < 3; ++c)
#pragma unroll
    for (int ky = 0; ky < 7; ++ky)
#pragma unroll
      for (int kx = 0; kx < 7; ++kx)
        acc += ins[c * 1480 + (row * 2 + ky) * 40 + (col * 2 + kx)] * wsm[c * 49 + ky * 7 + kx];
  out[(size_t)oc * 65536 + (size_t)(ty * 16 + row) * 256 + (tx * 16 + col)] = fmaxf(acc, 0.f);
}

// ---------------- maxpool 3x3 s2 pad1: [64,256,256] -> [64,128,128] ----------------
__launch_bounds__(256)
__global__ void maxpool_k(const float* __restrict__ in, float* __restrict__ out) {
  int idx = blockIdx.x * 256 + threadIdx.x;  // < 1048576
  int c = idx >> 14;
  int rem = idx & 16383;
  int y = rem >> 7, x = rem & 127;
  float m = -INFINITY;
#pragma unroll
  for (int dy = 0; dy < 3; ++dy) {
    int gy = 2 * y - 1 + dy;
    if ((unsigned)gy >= 256u) continue;
#pragma unroll
    for (int dx = 0; dx < 3; ++dx) {
      int gx = 2 * x - 1 + dx;
      if ((unsigned)gx >= 256u) continue;
      m = fmaxf(m, in[(size_t)c * 65536 + (size_t)gy * 256 + gx]);
    }
  }
  out[idx] = m;
}

// ---------------- generic 3x3 conv, pad 1 ----------------
// 128 threads, 32x32 output tile, 8 consecutive x-pixels per thread, OCB out channels.
// KSPLIT>1 -> writes partials [KSPLIT][COUT][HOUT*WOUT] without bias/relu.
template <int STRIDE, int CIN, int COUT, int OCB, int CC, int HIN, int WIN, int KSPLIT,
          bool HAS_BIAS, bool DO_RELU>
__launch_bounds__(128)
__global__ void conv3_k(const float* __restrict__ in, const float* __restrict__ wgt,
                        const float* __restrict__ bias, float* __restrict__ out) {
  constexpr int HOUT = (HIN - 1) / STRIDE + 1;
  constexpr int WOUT = (WIN - 1) / STRIDE + 1;
  constexpr int TY = HOUT / 32, TX = WOUT / 32, NT = TY * TX;
  constexpr int ITW = 31 * STRIDE + 3;   // valid input-tile width/height
  constexpr int ITH = 31 * STRIDE + 3;
  constexpr int ITWP = (STRIDE == 1) ? 36 : 68;  // padded row stride (16B aligned)
  constexpr int BPS = (COUT / OCB) * NT;
  constexpr int CSPL = CIN / KSPLIT;
  constexpr int IVW = (STRIDE == 1) ? 10 : 17;

  __shared__ __align__(16) float ins[CC * ITH * ITWP];
  __shared__ __align__(16) float wsm[OCB * CC * 12];

  const int bx = blockIdx.x;
  const int ks = bx / BPS;
  const int rr = bx - ks * BPS;
  const int ob = rr / NT;
  const int tt = rr - ob * NT;
  const int ty = tt / TX, tx = tt - (tt / TX) * TX;
  const int tid = threadIdx.x;
  const int row = tid >> 2;
  const int x0 = (tid & 3) * 8;

  float acc[OCB][8];
#pragma unroll
  for (int o = 0; o < OCB; ++o)
#pragma unroll
    for (int q = 0; q < 8; ++q) acc[o][q] = 0.f;

  const int iy0 = ty * 32 * STRIDE - 1;
  const int ix0 = tx * 32 * STRIDE - 1;
  const int cbeg = ks * CSPL;

  for (int cc = 0; cc < CSPL; cc += CC) {
    const int c0 = cbeg + cc;
    for (int idx = tid; idx < OCB * CC * 9; idx += 128) {
      int o = idx / (CC * 9);
      int r2 = idx - o * (CC * 9);
      int c = r2 / 9;
      int k = r2 - c * 9;
      wsm[(o * CC + c) * 12 + k] = wgt[((size_t)(ob * OCB + o) * CIN + (c0 + c)) * 9 + k];
    }
    for (int idx = tid; idx < CC * ITH * ITWP; idx += 128) {
      int c = idx / (ITH * ITWP);
      int r2 = idx - c * (ITH * ITWP);
      int iy = r2 / ITWP;
      int ix = r2 - iy * ITWP;
      int gy = iy0 + iy, gx = ix0 + ix;
      float v = 0.f;
      if (ix < ITW && (unsigned)gy < (unsigned)HIN && (unsigned)gx < (unsigned)WIN)
        v = in[(size_t)(c0 + c) * HIN * WIN + (size_t)gy * WIN + gx];
      ins[idx] = v;
    }
    __syncthreads();
#pragma unroll
    for (int c = 0; c < CC; ++c) {
      const float* ib = &ins[c * ITH * ITWP + (row * STRIDE) * ITWP + x0 * STRIDE];
      float iv[3][IVW];
#pragma unroll
      for (int ky = 0; ky < 3; ++ky) {
        const float* p = ib + ky * ITWP;
        if constexpr (STRIDE == 1) {
          float4 a = *(const float4*)p;
          float4 b = *(const float4*)(p + 4);
          float2 c2 = *(const float2*)(p + 8);
          iv[ky][0] = a.x; iv[ky][1] = a.y; iv[ky][2] = a.z; iv[ky][3] = a.w;
          iv[ky][4] = b.x; iv[ky][5] = b.y; iv[ky][6] = b.z; iv[ky][7] = b.w;
          iv[ky][8] = c2.x; iv[ky][9] = c2.y;
        } else {
          float4 a0 = *(const float4*)p;
          float4 a1 = *(const float4*)(p + 4);
          float4 a2 = *(const float4*)(p + 8);
          float4 a3 = *(const float4*)(p + 12);
          float a4 = p[16];
          iv[ky][0] = a0.x; iv[ky][1] = a0.y; iv[ky][2] = a0.z; iv[ky][3] = a0.w;
          iv[ky][4] = a1.x; iv[ky][5] = a1.y; iv[ky][6] = a1.z; iv[ky][7] = a1.w;
          iv[ky][8] = a2.x; iv[ky][9] = a2.y; iv[ky][10] = a2.z; iv[ky][11] = a2.w;
          iv[ky][12] = a3.x; iv[ky][13] = a3.y; iv[ky][14] = a3.z; iv[ky][15] = a3.w;
          iv[ky][16] = a4;
        }
      }
#pragma unroll
      for (int o = 0; o < OCB; ++o) {
        const float* wp = &wsm[(o * CC + c) * 12];
        float4 wA = *(const float4*)wp;
        float4 wB = *(const float4*)(wp + 4);
        float w8 = wp[8];
        float wk[9] = {wA.x, wA.y, wA.z, wA.w, wB.x, wB.y, wB.z, wB.w, w8};
#pragma unroll
        for (int q = 0; q < 8; ++q)
#pragma unroll
          for (int ky = 0; ky < 3; ++ky)
#pragma unroll
            for (int kx = 0; kx < 3; ++kx)
              acc[o][q] += iv[ky][q * STRIDE + kx] * wk[ky * 3 + kx];
      }
    }
    __syncthreads();
  }
  const int oy = ty * 32 + row;
  const int oxb = tx * 32 + x0;
  float* outp = out + (size_t)ks * COUT * HOUT * WOUT;
#pragma unroll
  for (int o = 0; o < OCB; ++o) {
    int oc = ob * OCB + o;
    float bv = HAS_BIAS ? bias[oc] : 0.f;
    float4 s0, s1;
    float v;
    v = acc[o][0] + bv; if (DO_RELU) v = fmaxf(v, 0.f); s0.x = v;
    v = acc[o][1] + bv; if (DO_RELU) v = fmaxf(v, 0.f); s0.y = v;
    v = acc[o][2] + bv; if (DO_RELU) v = fmaxf(v, 0.f); s0.z = v;
    v = acc[o][3] + bv; if (DO_RELU) v = fmaxf(v, 0.f); s0.w = v;
    v = acc[o][4] + bv; if (DO_RELU) v = fmaxf(v, 0.f); s1.x = v;
    v = acc[o][5] + bv; if (DO_RELU) v = fmaxf(v, 0.f); s1.y = v;
    v = acc[o][6] + bv; if (DO_RELU) v = fmaxf(v, 0.f); s1.z = v;
    v = acc[o][7] + bv; if (DO_RELU) v = fmaxf(v, 0.f); s1.w = v;
    size_t base = (size_t)oc * HOUT * WOUT + (size_t)oy * WOUT + oxb;
    *(float4*)&outp[base] = s0;
    *(float4*)&outp[base + 4] = s1;
  }
}

// ---------------- combine 4 k-split partials (+bias) + relu ----------------
__launch_bounds__(256)
__global__ void combine4_k(const float* __restrict__ p, const float* __restrict__ bias,
                           float* __restrict__ out, int hasBias) {
  int idx = blockIdx.x * 256 + threadIdx.x;  // < 2097152
  float v = p[idx] + p[2097152 + idx] + p[2 * 2097152 + idx] + p[3 * 2097152 + idx];
  if (hasBias) v += bias[idx >> 10];
  out[idx] = fmaxf(v, 0.f);
}

// ---------------- transpose feat [2048][1024] -> featT [1024][2048] ----------------
__launch_bounds__(256)
__global__ void transpose_k(const float* __restrict__ feat, float* __restrict__ featT) {
  __shared__ float t[32][33];
  int bi = blockIdx.x;
  int r0 = (bi >> 5) << 5;
  int c0 = (bi & 31) << 5;
  int tid = threadIdx.x;
#pragma unroll
  for (int k = 0; k < 4; ++k) {
    int idx = tid + k * 256;
    int rr = idx >> 5, cc = idx & 31;
    t[rr][cc] = feat[(size_t)(r0 + rr) * 1024 + c0 + cc];
  }
  __syncthreads();
#pragma unroll
  for (int k = 0; k < 4; ++k) {
    int idx = tid + k * 256;
    int rr = idx >> 5, cc = idx & 31;
    featT[(size_t)(c0 + rr) * 2048 + r0 + cc] = t[cc][rr];
  }
}

// ---------------- 1x1 conv head (obj/reg) ----------------
__launch_bounds__(256)
__global__ void conv1x1_k(const float* __restrict__ t, const float* __restrict__ w,
                          const float* __restrict__ b, float* __restrict__ out) {
  int a = blockIdx.x >> 2;
  int pix = ((blockIdx.x & 3) << 8) + threadIdx.x;
  const float* wr = w + (size_t)a * 2048;
  float acc = 0.f;
#pragma unroll 8
  for (int c = 0; c < 2048; ++c) acc += wr[c] * t[(size_t)c * 1024 + pix];
  out[a * 1024 + pix] = acc + b[a];
}

// ---------------- anchors + box decode + sortable keys ----------------
__launch_bounds__(256)
__global__ void decode_k(const float* __restrict__ obj, const float* __restrict__ reg,
                         float* __restrict__ boxes, unsigned long long* __restrict__ keys) {
  int i = blockIdx.x * 256 + threadIdx.x;  // < 12288
  int iy = i / 384;
  int r2 = i - iy * 384;
  int ix = r2 / 12;
  int a = r2 - ix * 12;
  int pix = iy * 32 + ix;
  float score = obj[a * 1024 + pix];
  float d0 = reg[(a * 4 + 0) * 1024 + pix];
  float d1 = reg[(a * 4 + 1) * 1024 + pix];
  float d2 = reg[(a * 4 + 2) * 1024 + pix];
  float d3 = reg[(a * 4 + 3) * 1024 + pix];
  int ridx = a >> 2, sidx = a & 3;
  float ratio = (ridx == 0) ? 0.5f : (ridx == 1) ? 1.0f : 2.0f;
  float scale = (sidx == 0) ? 32.f : (sidx == 1) ? 64.f : (sidx == 2) ? 128.f : 256.f;
  float hr = sqrtf(ratio);
  float wr = 1.f / hr;
  float ws_ = wr * scale, hs_ = hr * scale;
  float sx = ix * 16.f, sy = iy * 16.f;
  float ax0 = sx + (-ws_) / 2.f, ay0 = sy + (-hs_) / 2.f;
  float ax1 = sx + ws_ / 2.f, ay1 = sy + hs_ / 2.f;
  float wa = ax1 - ax0, ha = ay1 - ay0;
  float cxa = ax0 + 0.5f * wa, cya = ay0 + 0.5f * ha;
  const float CLAMP = 4.135166556742356f;  // log(1000/16)
  float dw = fminf(d2, CLAMP), dh = fminf(d3, CLAMP);
  float cx = d0 * wa + cxa, cy = d1 * ha + cya;
  float w_ = wa * expf(dw), h_ = ha * expf(dh);
  float bx0 = cx - 0.5f * w_, by0 = cy - 0.5f * h_;
  float bx1 = cx + 0.5f * w_, by1 = cy + 0.5f * h_;
  bx0 = fminf(fmaxf(bx0, 0.f), 512.f);
  by0 = fminf(fmaxf(by0, 0.f), 512.f);
  bx1 = fminf(fmaxf(bx1, 0.f), 512.f);
  by1 = fminf(fmaxf(by1, 0.f), 512.f);
  float4 b4;
  b4.x = bx0; b4.y = by0; b4.z = bx1; b4.w = by1;
  *(float4*)&boxes[i * 4] = b4;
  unsigned int u = __float_as_uint(score);
  unsigned int ord = u ^ ((u >> 31) ? 0xFFFFFFFFu : 0x80000000u);
  keys[i] = ((unsigned long long)ord << 32) | (unsigned long long)(0xFFFFFFFFu - (unsigned)i);
}

// ---------------- exact top-1000 by rank counting ----------------
__launch_bounds__(256)
__global__ void topk_k(const unsigned long long* __restrict__ keys,
                       const float* __restrict__ boxes, float* __restrict__ cand) {
  __shared__ unsigned long long sk[2048];
  int i = blockIdx.x * 256 + threadIdx.x;
  unsigned long long my = keys[i];
  int rank = 0;
  for (int base = 0; base < 12288; base += 2048) {
    for (int j = threadIdx.x; j < 2048; j += 256) sk[j] = keys[base + j];
    __syncthreads();
#pragma unroll 8
    for (int j = 0; j < 2048; ++j) rank += (sk[j] > my) ? 1 : 0;
    __syncthreads();
  }
  if (rank < 1000) {
    float4 b = *(const float4*)&boxes[i * 4];
    *(float4*)&cand[rank * 4] = b;
  }
}

// ---------------- suppression bitmask: sup[i][w] bits j (j>i, iou>0.7) ----------------
__launch_bounds__(64)
__global__ void iou_sup_k(const float* __restrict__ cand, unsigned long long* __restrict__ sup) {
  int i = blockIdx.x;
  int lane = threadIdx.x;
  float4 bi = *(const float4*)&cand[i * 4];
  float areai = (bi.z - bi.x) * (bi.w - bi.y);
  for (int cb = 0; cb < 16; ++cb) {
    int j = cb * 64 + lane;
    bool p = false;
    if (j < 1000 && j > i) {
      float4 bj = *(const float4*)&cand[j * 4];
      float areaj = (bj.z - bj.x) * (bj.w - bj.y);
      float lx = fmaxf(bi.x, bj.x), ly = fmaxf(bi.y, bj.y);
      float rx = fminf(bi.z, bj.z), ry = fminf(bi.w, bj.w);
      float iw = fmaxf(rx - lx, 0.f), ih = fmaxf(ry - ly, 0.f);
      float inter = iw * ih;
      float iou = inter / (areai + areaj - inter + 1e-9f);
      p = iou > 0.7f;
    }
    unsigned long long m = __ballot(p);
    if (lane == 0) sup[i * 16 + cb] = m;
  }
}

// ---------------- sequential greedy NMS + ordering + gather props ----------------
__launch_bounds__(64)
__global__ void nms_k(const float* __restrict__ cand, const unsigned long long* __restrict__ sup,
                      float* __restrict__ props) {
  volatile __shared__ unsigned long long keep[16];
  __shared__ int pidx[256];
  int tid = threadIdx.x;
  if (tid < 16) keep[tid] = (tid < 15) ? ~0ull : ((1ull << 40) - 1);
  __syncthreads();
  unsigned long long nxt = (tid < 16) ? sup[tid] : 0ull;
  for (int i = 0; i < 1000; ++i) {
    unsigned long long cur = nxt;
    if (i < 999 && tid < 16) nxt = sup[(size_t)(i + 1) * 16 + tid];
    bool alive = (keep[i >> 6] >> (i & 63)) & 1ull;
    if (alive && tid < 16) keep[tid] &= ~cur;
    __syncthreads();
  }
  if (tid == 0) {
    int cnt = 0;
    for (int pass = 0; pass < 2; ++pass)
      for (int i = 0; i < 1000 && cnt < 256; ++i) {
        bool a = (keep[i >> 6] >> (i & 63)) & 1ull;
        if (pass == 0 ? a : !a) pidx[cnt++] = i;
      }
  }
  __syncthreads();
  for (int k = 0; k < 4; ++k) {
    int r = k * 64 + tid;
    float4 b = *(const float4*)&cand[pidx[r] * 4];
    *(float4*)&props[r * 4] = b;
  }
}

// ---------------- ROI align: pooled[r][s][c] (c innermost, coalesced) ----------------
__launch_bounds__(256)
__global__ void roi_pool_k(const float* __restrict__ featT, const float* __restrict__ props,
                           float* __restrict__ pooled) {
  int r = blockIdx.x / 49;
  int s = blockIdx.x - r * 49;
  int py = s / 7, px = s - py * 7;
  float4 b = *(const float4*)&props[r * 4];
  float b0 = b.x * 0.0625f, b1 = b.y * 0.0625f, b2 = b.z * 0.0625f, b3 = b.w * 0.0625f;
  float gy = (py + 0.5f) / 7.f;
  float gx = (px + 0.5f) / 7.f;
  float yy = (b1 + gy * (b3 - b1)) - 0.5f;
  float xx = (b0 + gx * (b2 - b0)) - 0.5f;
  float y0f = floorf(yy), x0f = floorf(xx);
  float wy = yy - y0f, wx = xx - x0f;
  int y0 = min(max((int)y0f, 0), 31);
  int y1 = min(y0 + 1, 31);
  int x0 = min(max((int)x0f, 0), 31);
  int x1 = min(x0 + 1, 31);
  float w00 = (1.f - wy) * (1.f - wx), w01 = (1.f - wy) * wx;
  float w10 = wy * (1.f - wx), w11 = wy * wx;
  size_t i00 = (size_t)(y0 * 32 + x0) * 2048;
  size_t i01 = (size_t)(y0 * 32 + x1) * 2048;
  size_t i10 = (size_t)(y1 * 32 + x0) * 2048;
  size_t i11 = (size_t)(y1 * 32 + x1) * 2048;
  size_t outb = ((size_t)r * 49 + s) * 2048;
  for (int c = threadIdx.x; c < 2048; c += 256) {
    float v = featT[i00 + c] * w00 + featT[i01 + c] * w01 + featT[i10 + c] * w10 +
              featT[i11 + c] * w11;
    pooled[outb + c] = v;
  }
}

// ---------------- fc1: [256,100352] @ [100352,1024], k-split 16, partials ----------------
__launch_bounds__(256)
__global__ void fc1_gemm_k(const float* __restrict__ pooled, const float* __restrict__ w,
                           float* __restrict__ part) {
  __shared__ __align__(16) float As[8 * 128];
  __shared__ __align__(16) float Bs[8 * 132];
  int bx = blockIdx.x;
  int ks = bx >> 4;
  int mt = (bx >> 3) & 1;
  int nt = bx & 7;
  int m0 = mt * 128, n0 = nt * 128, k0 = ks * 6272;
  int tid = threadIdx.x;
  int tm = tid >> 4, tn = tid & 15;
  float acc[8][8];
#pragma unroll
  for (int i = 0; i < 8; ++i)
#pragma unroll
    for (int j = 0; j < 8; ++j) acc[i][j] = 0.f;
  int lam = tid >> 1, lak = (tid & 1) * 4;
  int lbk = tid >> 5, lbn = (tid & 31) * 4;
  for (int kb = 0; kb < 6272; kb += 8) {
    {
      float4 a = *(const float4*)&pooled[(size_t)(m0 + lam) * 100352 + k0 + kb + lak];
      As[(lak + 0) * 128 + lam] = a.x;
      As[(lak + 1) * 128 + lam] = a.y;
      As[(lak + 2) * 128 + lam] = a.z;
      As[(lak + 3) * 128 + lam] = a.w;
    }
    {
      int kk = k0 + kb + lbk;
      int row = (kk & 2047) * 49 + (kk >> 11);  // pooled col s*2048+c  ->  w row c*49+s
      float4 b = *(const float4*)&w[(size_t)row * 1024 + n0 + lbn];
      *(float4*)&Bs[lbk * 132 + lbn] = b;
    }
    __syncthreads();
#pragma unroll
    for (int k = 0; k < 8; ++k) {
      float a[8], bb[8];
      *(float4*)&a[0] = *(const float4*)&As[k * 128 + tm * 8];
      *(float4*)&a[4] = *(const float4*)&As[k * 128 + tm * 8 + 4];
      *(float4*)&bb[0] = *(const float4*)&Bs[k * 132 + tn * 8];
      *(float4*)&bb[4] = *(const float4*)&Bs[k * 132 + tn * 8 + 4];
#pragma unroll
      for (int i = 0; i < 8; ++i)
#pragma unroll
        for (int j = 0; j < 8; ++j) acc[i][j] += a[i] * bb[j];
    }
    __syncthreads();
  }
#pragma unroll
  for (int i = 0; i < 8; ++i)
#pragma unroll
    for (int j = 0; j < 8; ++j)
      part[((size_t)ks * 256 + m0 + tm * 8 + i) * 1024 + n0 + tn * 8 + j] = acc[i][j];
}

__launch_bounds__(256)
__global__ void fc1_reduce_k(const float* __restrict__ part, const float* __restrict__ bias,
                             float* __restrict__ h1) {
  int idx = blockIdx.x * 256 + threadIdx.x;  // < 262144
  int n = idx & 1023;
  float v = bias[n];
#pragma unroll
  for (int ks = 0; ks < 16; ++ks) v += part[(size_t)ks * 262144 + idx];
  h1[idx] = v;  // relu applied on load in fc2
}

// ---------------- fc2: relu(h1) @ [1024,1024] + b ----------------
__launch_bounds__(256)
__global__ void fc2_k(const float* __restrict__ h1, const float* __restrict__ w,
                      const float* __restrict__ b, float* __restrict__ h2) {
  __shared__ float hs[1024];
  int r = blockIdx.x;
  int tid = threadIdx.x;
  for (int k = tid; k < 1024; k += 256) hs[k] = fmaxf(h1[(size_t)r * 1024 + k], 0.f);
  __syncthreads();
  float acc0 = 0.f, acc1 = 0.f, acc2 = 0.f, acc3 = 0.f;
#pragma unroll 4
  for (int k = 0; k < 1024; ++k) {
    float hv = hs[k];
    const float* wr = w + (size_t)k * 1024;
    acc0 += hv * wr[tid];
    acc1 += hv * wr[tid + 256];
    acc2 += hv * wr[tid + 512];
    acc3 += hv * wr[tid + 768];
  }
  h2[(size_t)r * 1024 + tid] = acc0 + b[tid];
  h2[(size_t)r * 1024 + tid + 256] = acc1 + b[tid + 256];
  h2[(size_t)r * 1024 + tid + 512] = acc2 + b[tid + 512];
  h2[(size_t)r * 1024 + tid + 768] = acc3 + b[tid + 768];
}

// ---------------- heads: relu(h2) @ cls/box, concat -> out[256,455] ----------------
__launch_bounds__(256)
__global__ void head_k(const float* __restrict__ h2, const float* __restrict__ cls_w,
                       const float* __restrict__ cls_b, const float* __restrict__ box_w,
                       const float* __restrict__ box_b, float* __restrict__ out) {
  __shared__ float hs[1024];
  int r = blockIdx.x;
  int tid = threadIdx.x;
  for (int k = tid; k < 1024; k += 256) hs[k] = fmaxf(h2[(size_t)r * 1024 + k], 0.f);
  __syncthreads();
  for (int n = tid; n < 455; n += 256) {
    float acc = 0.f;
    if (n < 91) {
#pragma unroll 4
      for (int k = 0; k < 1024; ++k) acc += hs[k] * cls_w[(size_t)k * 91 + n];
      acc += cls_b[n];
    } else {
      int nb = n - 91;
#pragma unroll 4
      for (int k = 0; k < 1024; ++k) acc += hs[k] * box_w[(size_t)k * 364 + nb];
      acc += box_b[nb];
    }
    out[(size_t)r * 455 + n] = acc;
  }
}

// ---------------- launcher ----------------
extern "C" void kernel_launch(void* const* d_in, const int* in_sizes, int n_in, void* d_out,
                              int out_size, void* d_ws, size_t ws_size, hipStream_t stream) {
  const float* img    = (const float*)d_in[0];
  const float* w_stem = (const float*)d_in[1];
  const float* w1     = (const float*)d_in[2];
  const float* w2     = (const float*)d_in[3];
  const float* w3     = (const float*)d_in[4];
  const float* w4     = (const float*)d_in[5];
  const float* w_rpn  = (const float*)d_in[6];
  const float* b_rpn  = (const float*)d_in[7];
  const float* w_obj  = (const float*)d_in[8];
  const float* b_obj  = (const float*)d_in[9];
  const float* w_reg  = (const float*)d_in[10];
  const float* b_regc = (const float*)d_in[11];
  const float* fc1_w  = (const float*)d_in[12];
  const float* fc1_b  = (const float*)d_in[13];
  const float* fc2_w  = (const float*)d_in[14];
  const float* fc2_b  = (const float*)d_in[15];
  const float* cls_w  = (const float*)d_in[16];
  const float* cls_b  = (const float*)d_in[17];
  const float* box_w  = (const float*)d_in[18];
  const float* box_b  = (const float*)d_in[19];
  float* W = (float*)d_ws;
  float* out = (float*)d_out;

  stem_k<<<64 * 256, 256, 0, stream>>>(img, w_stem, W + BIGA);
  maxpool_k<<<4096, 256, 0, stream>>>(W + BIGA, W + BIGB);
  conv3_k<1, 64, 256, 4, 4, 128, 128, 1, false, true>
      <<<1024, 128, 0, stream>>>(W + BIGB, w1, nullptr, W + BIGA);
  conv3_k<2, 256, 512, 4, 2, 128, 128, 1, false, true>
      <<<512, 128, 0, stream>>>(W + BIGA, w2, nullptr, W + BIGB);
  conv3_k<2, 512, 1024, 2, 2, 64, 64, 1, false, true>
      <<<512, 128, 0, stream>>>(W + BIGB, w3, nullptr, W + BIGC);
  conv3_k<1, 1024, 2048, 8, 4, 32, 32, 4, false, false>
      <<<1024, 128, 0, stream>>>(W + BIGC, w4, nullptr, W + PARTO);
  combine4_k<<<8192, 256, 0, stream>>>(W + PARTO, nullptr, W + FEATO, 0);
  transpose_k<<<2048, 256, 0, stream>>>(W + FEATO, W + FEATT);
  conv3_k<1, 2048, 2048, 8, 4, 32, 32, 4, false, false>
      <<<1024, 128, 0, stream>>>(W + FEATO, w_rpn, nullptr, W + PARTO);
  combine4_k<<<8192, 256, 0, stream>>>(W + PARTO, b_rpn, W + BIGB, 1);  // T = BIGB
  conv1x1_k<<<12 * 4, 256, 0, stream>>>(W + BIGB, w_obj, b_obj, W + OBJO);
  conv1x1_k<<<48 * 4, 256, 0, stream>>>(W + BIGB, w_reg, b_regc, W + REGO);
  decode_k<<<48, 256, 0, stream>>>(W + OBJO, W + REGO, W + BOXO,
                                   (unsigned long long*)(W + KEYO));
  topk_k<<<48, 256, 0, stream>>>((const unsigned long long*)(W + KEYO), W + BOXO, W + CANDO);
  iou_sup_k<<<1000, 64, 0, stream>>>(W + CANDO, (unsigned long long*)(W + SUPO));
  nms_k<<<1, 64, 0, stream>>>(W + CANDO, (const unsigned long long*)(W + SUPO), W + PROPO);
  roi_pool_k<<<256 * 49, 256, 0, stream>>>(W + FEATT, W + PROPO, W + POOLO);
  fc1_gemm_k<<<256, 256, 0, stream>>>(W + POOLO, fc1_w, W + FC1PO);
  fc1_reduce_k<<<1024, 256, 0, stream>>>(W + FC1PO, fc1_b, W + H1O);
  fc2_k<<<256, 256, 0, stream>>>(W + H1O, fc2_w, fc2_b, W + H2O);
  head_k<<<256, 256, 0, stream>>>(W + H2O, cls_w, cls_b, box_w, box_b, out);
}

// Round 3
// 7452.052 us; speedup vs baseline: 2.1130x; 2.1130x over previous
//
#include <hip/hip_runtime.h>
#include <cstddef>

// ---------------- workspace layout (float offsets) ----------------
static constexpr size_t BIGA   = 0;              // 4194304  stem out / c1 out
static constexpr size_t BIGB   = 4194304;        // 2097152  pool / c2 / T
static constexpr size_t BIGC   = 6291456;        // 1048576  c3 out
static constexpr size_t FEATO  = 7340032;        // 2097152  feat [2048][1024]
static constexpr size_t FEATT  = 9437184;        // 2097152  featT [1024][2048]
static constexpr size_t OBJO   = 11534336;       // 12288
static constexpr size_t REGO   = 11546624;       // 49152
static constexpr size_t BOXO   = 11595776;       // 49152
static constexpr size_t KEYO   = 11644928;       // 24576 (u64 x 12288)
static constexpr size_t CANDO  = 11669504;       // 4000
static constexpr size_t SUPO   = 11673504;       // 32000 (u64 x 16000)
static constexpr size_t PROPO  = 11705504;       // 1024
static constexpr size_t POOLO  = 11706528;       // 25690112 [256][49][2048]
static constexpr size_t PARTO  = POOLO;          // alias: conv k-split partials (<=16777216), dead before pooled
static constexpr size_t FC1PO  = 37396640;       // 4194304 [16][256][1024]
static constexpr size_t H1O    = 41590944;       // 262144
static constexpr size_t H2O    = 41853088;       // 262144
// total 42115232 floats = 161 MiB

// ---------------- stem: 7x7 s2 pad3, Cin=3 -> [64,256,256], relu ----------------
__launch_bounds__(256)
__global__ void stem_k(const float* __restrict__ img, const float* __restrict__ w,
                       float* __restrict__ out) {
  __shared__ float ins[3 * 37 * 40];
  __shared__ float wsm[160];
  int bx = blockIdx.x;
  int oc = bx >> 8;
  int t = bx & 255;
  int ty = t >> 4, tx = t & 15;
  int tid = threadIdx.x;
  for (int idx = tid; idx < 147; idx += 256) wsm[idx] = w[oc * 147 + idx];
  int iy0 = ty * 32 - 3, ix0 = tx * 32 - 3;
  for (int idx = tid; idx < 3 * 37 * 40; idx += 256) {
    int c = idx / 1480;
    int r = idx - c * 1480;
    int iy = r / 40, ix = r - iy * 40;
    int gy = iy0 + iy, gx = ix0 + ix;
    float v = 0.f;
    if (ix < 37 && (unsigned)gy < 512u && (unsigned)gx < 512u)
      v = img[(size_t)c * 262144 + (size_t)gy * 512 + gx];
    ins[idx] = v;
  }
  __syncthreads();
  int row = tid >> 4, col = tid & 15;
  float acc = 0.f;
#pragma unroll
  for (int c = 0; c < 3; ++c)
#pragma unroll
    for (int ky = 0; ky < 7; ++ky)
#pragma unroll
      for (int kx = 0; kx < 7; ++kx)
        acc += ins[c * 1480 + (row * 2 + ky) * 40 + (col * 2 + kx)] * wsm[c * 49 + ky * 7 + kx];
  out[(size_t)oc * 65536 + (size_t)(ty * 16 + row) * 256 + (tx * 16 + col)] = fmaxf(acc, 0.f);
}

// ---------------- maxpool 3x3 s2 pad1: [64,256,256] -> [64,128,128] ----------------
__launch_bounds__(256)
__global__ void maxpool_k(const float* __restrict__ in, float* __restrict__ out) {
  int idx = blockIdx.x * 256 + threadIdx.x;  // < 1048576
  int c = idx >> 14;
  int rem = idx & 16383;
  int y = rem >> 7, x = rem & 127;
  float m = -INFINITY;
#pragma unroll
  for (int dy = 0; dy < 3; ++dy) {
    int gy = 2 * y - 1 + dy;
    if ((unsigned)gy >= 256u) continue;
#pragma unroll
    for (int dx = 0; dx < 3; ++dx) {
      int gx = 2 * x - 1 + dx;
      if ((unsigned)gx >= 256u) continue;
      m = fmaxf(m, in[(size_t)c * 65536 + (size_t)gy * 256 + gx]);
    }
  }
  out[idx] = m;
}

// ---------------- generic 3x3 conv stride 1, pad 1 (LDS-staged) ----------------
template <int STRIDE, int CIN, int COUT, int OCB, int CC, int HIN, int WIN, int KSPLIT,
          bool HAS_BIAS, bool DO_RELU>
__launch_bounds__(128)
__global__ void conv3_k(const float* __restrict__ in, const float* __restrict__ wgt,
                        const float* __restrict__ bias, float* __restrict__ out) {
  constexpr int HOUT = (HIN - 1) / STRIDE + 1;
  constexpr int WOUT = (WIN - 1) / STRIDE + 1;
  constexpr int TY = HOUT / 32, TX = WOUT / 32, NT = TY * TX;
  constexpr int ITW = 31 * STRIDE + 3;
  constexpr int ITH = 31 * STRIDE + 3;
  constexpr int ITWP = (STRIDE == 1) ? 36 : 68;
  constexpr int BPS = (COUT / OCB) * NT;
  constexpr int CSPL = CIN / KSPLIT;
  constexpr int IVW = (STRIDE == 1) ? 10 : 17;

  __shared__ __align__(16) float ins[CC * ITH * ITWP];
  __shared__ __align__(16) float wsm[OCB * CC * 12];

  const int bx = blockIdx.x;
  const int ks = bx / BPS;
  const int rr = bx - ks * BPS;
  const int ob = rr / NT;
  const int tt = rr - ob * NT;
  const int ty = tt / TX, tx = tt - (tt / TX) * TX;
  const int tid = threadIdx.x;
  const int row = tid >> 2;
  const int x0 = (tid & 3) * 8;

  float acc[OCB][8];
#pragma unroll
  for (int o = 0; o < OCB; ++o)
#pragma unroll
    for (int q = 0; q < 8; ++q) acc[o][q] = 0.f;

  const int iy0 = ty * 32 * STRIDE - 1;
  const int ix0 = tx * 32 * STRIDE - 1;
  const int cbeg = ks * CSPL;

  for (int cc = 0; cc < CSPL; cc += CC) {
    const int c0 = cbeg + cc;
    for (int idx = tid; idx < OCB * CC * 9; idx += 128) {
      int o = idx / (CC * 9);
      int r2 = idx - o * (CC * 9);
      int c = r2 / 9;
      int k = r2 - c * 9;
      wsm[(o * CC + c) * 12 + k] = wgt[((size_t)(ob * OCB + o) * CIN + (c0 + c)) * 9 + k];
    }
    for (int idx = tid; idx < CC * ITH * ITWP; idx += 128) {
      int c = idx / (ITH * ITWP);
      int r2 = idx - c * (ITH * ITWP);
      int iy = r2 / ITWP;
      int ix = r2 - iy * ITWP;
      int gy = iy0 + iy, gx = ix0 + ix;
      float v = 0.f;
      if (ix < ITW && (unsigned)gy < (unsigned)HIN && (unsigned)gx < (unsigned)WIN)
        v = in[(size_t)(c0 + c) * HIN * WIN + (size_t)gy * WIN + gx];
      ins[idx] = v;
    }
    __syncthreads();
#pragma unroll
    for (int c = 0; c < CC; ++c) {
      const float* ib = &ins[c * ITH * ITWP + (row * STRIDE) * ITWP + x0 * STRIDE];
      float iv[3][IVW];
#pragma unroll
      for (int ky = 0; ky < 3; ++ky) {
        const float* p = ib + ky * ITWP;
        if constexpr (STRIDE == 1) {
          float4 a = *(const float4*)p;
          float4 b = *(const float4*)(p + 4);
          float2 c2 = *(const float2*)(p + 8);
          iv[ky][0] = a.x; iv[ky][1] = a.y; iv[ky][2] = a.z; iv[ky][3] = a.w;
          iv[ky][4] = b.x; iv[ky][5] = b.y; iv[ky][6] = b.z; iv[ky][7] = b.w;
          iv[ky][8] = c2.x; iv[ky][9] = c2.y;
        } else {
          float4 a0 = *(const float4*)p;
          float4 a1 = *(const float4*)(p + 4);
          float4 a2 = *(const float4*)(p + 8);
          float4 a3 = *(const float4*)(p + 12);
          float a4 = p[16];
          iv[ky][0] = a0.x; iv[ky][1] = a0.y; iv[ky][2] = a0.z; iv[ky][3] = a0.w;
          iv[ky][4] = a1.x; iv[ky][5] = a1.y; iv[ky][6] = a1.z; iv[ky][7] = a1.w;
          iv[ky][8] = a2.x; iv[ky][9] = a2.y; iv[ky][10] = a2.z; iv[ky][11] = a2.w;
          iv[ky][12] = a3.x; iv[ky][13] = a3.y; iv[ky][14] = a3.z; iv[ky][15] = a3.w;
          iv[ky][16] = a4;
        }
      }
#pragma unroll
      for (int o = 0; o < OCB; ++o) {
        const float* wp = &wsm[(o * CC + c) * 12];
        float4 wA = *(const float4*)wp;
        float4 wB = *(const float4*)(wp + 4);
        float w8 = wp[8];
        float wk[9] = {wA.x, wA.y, wA.z, wA.w, wB.x, wB.y, wB.z, wB.w, w8};
#pragma unroll
        for (int q = 0; q < 8; ++q)
#pragma unroll
          for (int ky = 0; ky < 3; ++ky)
#pragma unroll
            for (int kx = 0; kx < 3; ++kx)
              acc[o][q] += iv[ky][q * STRIDE + kx] * wk[ky * 3 + kx];
      }
    }
    __syncthreads();
  }
  const int oy = ty * 32 + row;
  const int oxb = tx * 32 + x0;
  float* outp = out + (size_t)ks * COUT * HOUT * WOUT;
#pragma unroll
  for (int o = 0; o < OCB; ++o) {
    int oc = ob * OCB + o;
    float bv = HAS_BIAS ? bias[oc] : 0.f;
    float4 s0, s1;
    float v;
    v = acc[o][0] + bv; if (DO_RELU) v = fmaxf(v, 0.f); s0.x = v;
    v = acc[o][1] + bv; if (DO_RELU) v = fmaxf(v, 0.f); s0.y = v;
    v = acc[o][2] + bv; if (DO_RELU) v = fmaxf(v, 0.f); s0.z = v;
    v = acc[o][3] + bv; if (DO_RELU) v = fmaxf(v, 0.f); s0.w = v;
    v = acc[o][4] + bv; if (DO_RELU) v = fmaxf(v, 0.f); s1.x = v;
    v = acc[o][5] + bv; if (DO_RELU) v = fmaxf(v, 0.f); s1.y = v;
    v = acc[o][6] + bv; if (DO_RELU) v = fmaxf(v, 0.f); s1.z = v;
    v = acc[o][7] + bv; if (DO_RELU) v = fmaxf(v, 0.f); s1.w = v;
    size_t base = (size_t)oc * HOUT * WOUT + (size_t)oy * WOUT + oxb;
    *(float4*)&outp[base] = s0;
    *(float4*)&outp[base + 4] = s1;
  }
}

// ---------------- stride-2 3x3 conv, pad 1: direct-global reads, no input LDS ----
// 256 threads; thread = (x in 0..31, rowgroup 0..7 -> 4 output rows); OCB=8.
// Writes partials [KSPLIT][COUT][HOUT*WOUT].
template <int CIN, int COUT, int HIN, int WIN, int KSPLIT>
__launch_bounds__(256)
__global__ void conv3s2_k(const float* __restrict__ in, const float* __restrict__ wgt,
                          float* __restrict__ out) {
  constexpr int HOUT = HIN / 2, WOUT = WIN / 2;
  constexpr int TY = HOUT / 32, TX = WOUT / 32, NT = TY * TX;
  constexpr int CSPL = CIN / KSPLIT;
  constexpr int BPS = (COUT / 8) * NT;
  __shared__ __align__(16) float wlds[CSPL * 72];  // [c][k(9)][oc(8)]
  const int bx = blockIdx.x;
  const int ks = bx / BPS;
  const int rr = bx - ks * BPS;
  const int ob = rr / NT;
  const int tt = rr - ob * NT;
  const int ty = tt / TX, tx = tt - (tt / TX) * TX;
  const int tid = threadIdx.x;
  const int x = tid & 31, rg = tid >> 5;
  const int cbeg = ks * CSPL;
  for (int idx = tid; idx < CSPL * 72; idx += 256) {
    int c = idx / 72;
    int rem = idx - c * 72;
    int k = rem >> 3, oc = rem & 7;
    wlds[idx] = wgt[((size_t)(ob * 8 + oc) * CIN + cbeg + c) * 9 + k];
  }
  __syncthreads();
  const int oybase = ty * 32 + rg * 4;
  const int oxx = tx * 32 + x;
  const int ybase = 2 * oybase - 1;
  const int xbase = 2 * oxx - 1;
  int rowoff[9];
#pragma unroll
  for (int t = 0; t < 9; ++t) rowoff[t] = max(ybase + t, 0) * WIN;
  const int x0c = max(xbase, 0);
  const float my0 = (ybase >= 0) ? 1.f : 0.f;
  const float mx0 = (xbase >= 0) ? 1.f : 0.f;
  float acc[8][4];
#pragma unroll
  for (int o = 0; o < 8; ++o)
#pragma unroll
    for (int j = 0; j < 4; ++j) acc[o][j] = 0.f;
  const float* ip = in + (size_t)cbeg * HIN * WIN;
  for (int c = 0; c < CSPL; ++c, ip += HIN * WIN) {
    float iv[9][3];
#pragma unroll
    for (int t = 0; t < 9; ++t) {
      const float* rp = ip + rowoff[t];
      iv[t][0] = rp[x0c];
      iv[t][1] = rp[xbase + 1];
      iv[t][2] = rp[xbase + 2];
    }
#pragma unroll
    for (int t = 0; t < 9; ++t) iv[t][0] *= mx0;   // left-edge mask
    iv[0][0] *= my0; iv[0][1] *= my0; iv[0][2] *= my0;  // top-edge mask
    const float* wp0 = &wlds[c * 72];
#pragma unroll
    for (int ky = 0; ky < 3; ++ky)
#pragma unroll
      for (int kx = 0; kx < 3; ++kx) {
        const float* wp = wp0 + (ky * 3 + kx) * 8;
        float4 wa = *(const float4*)wp;
        float4 wb = *(const float4*)(wp + 4);
#pragma unroll
        for (int j = 0; j < 4; ++j) {
          float v = iv[2 * j + ky][kx];
          acc[0][j] += v * wa.x; acc[1][j] += v * wa.y;
          acc[2][j] += v * wa.z; acc[3][j] += v * wa.w;
          acc[4][j] += v * wb.x; acc[5][j] += v * wb.y;
          acc[6][j] += v * wb.z; acc[7][j] += v * wb.w;
        }
      }
  }
#pragma unroll
  for (int oc = 0; oc < 8; ++oc)
#pragma unroll
    for (int j = 0; j < 4; ++j)
      out[((size_t)ks * COUT + ob * 8 + oc) * (HOUT * WOUT) +
          (size_t)(oybase + j) * WOUT + oxx] = acc[oc][j];
}

// ---------------- combine N k-split partials (+bias) + relu ----------------
template <int N, int CHUNK, bool HAS_BIAS>
__launch_bounds__(256)
__global__ void combN_k(const float* __restrict__ p, const float* __restrict__ bias,
                        float* __restrict__ out) {
  int idx = blockIdx.x * 256 + threadIdx.x;
  float v = HAS_BIAS ? bias[idx >> 10] : 0.f;
#pragma unroll
  for (int k = 0; k < N; ++k) v += p[(size_t)k * CHUNK + idx];
  out[idx] = fmaxf(v, 0.f);
}

// ---------------- transpose feat [2048][1024] -> featT [1024][2048] ----------------
__launch_bounds__(256)
__global__ void transpose_k(const float* __restrict__ feat, float* __restrict__ featT) {
  __shared__ float t[32][33];
  int bi = blockIdx.x;
  int r0 = (bi >> 5) << 5;
  int c0 = (bi & 31) << 5;
  int tid = threadIdx.x;
#pragma unroll
  for (int k = 0; k < 4; ++k) {
    int idx = tid + k * 256;
    int rr = idx >> 5, cc = idx & 31;
    t[rr][cc] = feat[(size_t)(r0 + rr) * 1024 + c0 + cc];
  }
  __syncthreads();
#pragma unroll
  for (int k = 0; k < 4; ++k) {
    int idx = tid + k * 256;
    int rr = idx >> 5, cc = idx & 31;
    featT[(size_t)(c0 + rr) * 2048 + r0 + cc] = t[cc][rr];
  }
}

// ---------------- 1x1 conv head (obj/reg) ----------------
__launch_bounds__(256)
__global__ void conv1x1_k(const float* __restrict__ t, const float* __restrict__ w,
                          const float* __restrict__ b, float* __restrict__ out) {
  int a = blockIdx.x >> 2;
  int pix = ((blockIdx.x & 3) << 8) + threadIdx.x;
  const float* wr = w + (size_t)a * 2048;
  float acc = 0.f;
#pragma unroll 8
  for (int c = 0; c < 2048; ++c) acc += wr[c] * t[(size_t)c * 1024 + pix];
  out[a * 1024 + pix] = acc + b[a];
}

// ---------------- anchors + box decode + sortable keys ----------------
__launch_bounds__(256)
__global__ void decode_k(const float* __restrict__ obj, const float* __restrict__ reg,
                         float* __restrict__ boxes, unsigned long long* __restrict__ keys) {
  int i = blockIdx.x * 256 + threadIdx.x;  // < 12288
  int iy = i / 384;
  int r2 = i - iy * 384;
  int ix = r2 / 12;
  int a = r2 - ix * 12;
  int pix = iy * 32 + ix;
  float score = obj[a * 1024 + pix];
  float d0 = reg[(a * 4 + 0) * 1024 + pix];
  float d1 = reg[(a * 4 + 1) * 1024 + pix];
  float d2 = reg[(a * 4 + 2) * 1024 + pix];
  float d3 = reg[(a * 4 + 3) * 1024 + pix];
  int ridx = a >> 2, sidx = a & 3;
  float ratio = (ridx == 0) ? 0.5f : (ridx == 1) ? 1.0f : 2.0f;
  float scale = (sidx == 0) ? 32.f : (sidx == 1) ? 64.f : (sidx == 2) ? 128.f : 256.f;
  float hr = sqrtf(ratio);
  float wr = 1.f / hr;
  float ws_ = wr * scale, hs_ = hr * scale;
  float sx = ix * 16.f, sy = iy * 16.f;
  float ax0 = sx + (-ws_) / 2.f, ay0 = sy + (-hs_) / 2.f;
  float ax1 = sx + ws_ / 2.f, ay1 = sy + hs_ / 2.f;
  float wa = ax1 - ax0, ha = ay1 - ay0;
  float cxa = ax0 + 0.5f * wa, cya = ay0 + 0.5f * ha;
  const float CLAMP = 4.135166556742356f;  // log(1000/16)
  float dw = fminf(d2, CLAMP), dh = fminf(d3, CLAMP);
  float cx = d0 * wa + cxa, cy = d1 * ha + cya;
  float w_ = wa * expf(dw), h_ = ha * expf(dh);
  float bx0 = cx - 0.5f * w_, by0 = cy - 0.5f * h_;
  float bx1 = cx + 0.5f * w_, by1 = cy + 0.5f * h_;
  bx0 = fminf(fmaxf(bx0, 0.f), 512.f);
  by0 = fminf(fmaxf(by0, 0.f), 512.f);
  bx1 = fminf(fmaxf(bx1, 0.f), 512.f);
  by1 = fminf(fmaxf(by1, 0.f), 512.f);
  float4 b4;
  b4.x = bx0; b4.y = by0; b4.z = bx1; b4.w = by1;
  *(float4*)&boxes[i * 4] = b4;
  unsigned int u = __float_as_uint(score);
  unsigned int ord = u ^ ((u >> 31) ? 0xFFFFFFFFu : 0x80000000u);
  keys[i] = ((unsigned long long)ord << 32) | (unsigned long long)(0xFFFFFFFFu - (unsigned)i);
}

// ---------------- exact top-1000 by rank counting ----------------
__launch_bounds__(256)
__global__ void topk_k(const unsigned long long* __restrict__ keys,
                       const float* __restrict__ boxes, float* __restrict__ cand) {
  __shared__ unsigned long long sk[2048];
  int i = blockIdx.x * 256 + threadIdx.x;
  unsigned long long my = keys[i];
  int rank = 0;
  for (int base = 0; base < 12288; base += 2048) {
    for (int j = threadIdx.x; j < 2048; j += 256) sk[j] = keys[base + j];
    __syncthreads();
#pragma unroll 8
    for (int j = 0; j < 2048; ++j) rank += (sk[j] > my) ? 1 : 0;
    __syncthreads();
  }
  if (rank < 1000) {
    float4 b = *(const float4*)&boxes[i * 4];
    *(float4*)&cand[rank * 4] = b;
  }
}

// ---------------- suppression bitmask: sup[i][w] bits j (j>i, iou>0.7) ----------------
__launch_bounds__(64)
__global__ void iou_sup_k(const float* __restrict__ cand, unsigned long long* __restrict__ sup) {
  int i = blockIdx.x;
  int lane = threadIdx.x;
  float4 bi = *(const float4*)&cand[i * 4];
  float areai = (bi.z - bi.x) * (bi.w - bi.y);
  for (int cb = 0; cb < 16; ++cb) {
    int j = cb * 64 + lane;
    bool p = false;
    if (j < 1000 && j > i) {
      float4 bj = *(const float4*)&cand[j * 4];
      float areaj = (bj.z - bj.x) * (bj.w - bj.y);
      float lx = fmaxf(bi.x, bj.x), ly = fmaxf(bi.y, bj.y);
      float rx = fminf(bi.z, bj.z), ry = fminf(bi.w, bj.w);
      float iw = fmaxf(rx - lx, 0.f), ih = fmaxf(ry - ly, 0.f);
      float inter = iw * ih;
      float iou = inter / (areai + areaj - inter + 1e-9f);
      p = iou > 0.7f;
    }
    unsigned long long m = __ballot(p);
    if (lane == 0) sup[i * 16 + cb] = m;
  }
}

// ---------------- sequential greedy NMS + ordering + gather props ----------------
__launch_bounds__(64)
__global__ void nms_k(const float* __restrict__ cand, const unsigned long long* __restrict__ sup,
                      float* __restrict__ props) {
  volatile __shared__ unsigned long long keep[16];
  __shared__ int pidx[256];
  int tid = threadIdx.x;
  if (tid < 16) keep[tid] = (tid < 15) ? ~0ull : ((1ull << 40) - 1);
  __syncthreads();
  unsigned long long nxt = (tid < 16) ? sup[tid] : 0ull;
  for (int i = 0; i < 1000; ++i) {
    unsigned long long cur = nxt;
    if (i < 999 && tid < 16) nxt = sup[(size_t)(i + 1) * 16 + tid];
    bool alive = (keep[i >> 6] >> (i & 63)) & 1ull;
    if (alive && tid < 16) keep[tid] &= ~cur;
    __syncthreads();
  }
  if (tid == 0) {
    int cnt = 0;
    for (int pass = 0; pass < 2; ++pass)
      for (int i = 0; i < 1000 && cnt < 256; ++i) {
        bool a = (keep[i >> 6] >> (i & 63)) & 1ull;
        if (pass == 0 ? a : !a) pidx[cnt++] = i;
      }
  }
  __syncthreads();
  for (int k = 0; k < 4; ++k) {
    int r = k * 64 + tid;
    float4 b = *(const float4*)&cand[pidx[r] * 4];
    *(float4*)&props[r * 4] = b;
  }
}

// ---------------- ROI align: pooled[r][s][c] (c innermost, coalesced) ----------------
__launch_bounds__(256)
__global__ void roi_pool_k(const float* __restrict__ featT, const float* __restrict__ props,
                           float* __restrict__ pooled) {
  int r = blockIdx.x / 49;
  int s = blockIdx.x - r * 49;
  int py = s / 7, px = s - py * 7;
  float4 b = *(const float4*)&props[r * 4];
  float b0 = b.x * 0.0625f, b1 = b.y * 0.0625f, b2 = b.z * 0.0625f, b3 = b.w * 0.0625f;
  float gy = (py + 0.5f) / 7.f;
  float gx = (px + 0.5f) / 7.f;
  float yy = (b1 + gy * (b3 - b1)) - 0.5f;
  float xx = (b0 + gx * (b2 - b0)) - 0.5f;
  float y0f = floorf(yy), x0f = floorf(xx);
  float wy = yy - y0f, wx = xx - x0f;
  int y0 = min(max((int)y0f, 0), 31);
  int y1 = min(y0 + 1, 31);
  int x0 = min(max((int)x0f, 0), 31);
  int x1 = min(x0 + 1, 31);
  float w00 = (1.f - wy) * (1.f - wx), w01 = (1.f - wy) * wx;
  float w10 = wy * (1.f - wx), w11 = wy * wx;
  size_t i00 = (size_t)(y0 * 32 + x0) * 2048;
  size_t i01 = (size_t)(y0 * 32 + x1) * 2048;
  size_t i10 = (size_t)(y1 * 32 + x0) * 2048;
  size_t i11 = (size_t)(y1 * 32 + x1) * 2048;
  size_t outb = ((size_t)r * 49 + s) * 2048;
  for (int c = threadIdx.x; c < 2048; c += 256) {
    float v = featT[i00 + c] * w00 + featT[i01 + c] * w01 + featT[i10 + c] * w10 +
              featT[i11 + c] * w11;
    pooled[outb + c] = v;
  }
}

// ---------------- fc1: [256,100352] @ [100352,1024], k-split 16, partials ----------------
__launch_bounds__(256)
__global__ void fc1_gemm_k(const float* __restrict__ pooled, const float* __restrict__ w,
                           float* __restrict__ part) {
  __shared__ __align__(16) float As[8 * 128];
  __shared__ __align__(16) float Bs[8 * 132];
  int bx = blockIdx.x;
  int ks = bx >> 4;
  int mt = (bx >> 3) & 1;
  int nt = bx & 7;
  int m0 = mt * 128, n0 = nt * 128, k0 = ks * 6272;
  int tid = threadIdx.x;
  int tm = tid >> 4, tn = tid & 15;
  float acc[8][8];
#pragma unroll
  for (int i = 0; i < 8; ++i)
#pragma unroll
    for (int j = 0; j < 8; ++j) acc[i][j] = 0.f;
  int lam = tid >> 1, lak = (tid & 1) * 4;
  int lbk = tid >> 5, lbn = (tid & 31) * 4;
  for (int kb = 0; kb < 6272; kb += 8) {
    {
      float4 a = *(const float4*)&pooled[(size_t)(m0 + lam) * 100352 + k0 + kb + lak];
      As[(lak + 0) * 128 + lam] = a.x;
      As[(lak + 1) * 128 + lam] = a.y;
      As[(lak + 2) * 128 + lam] = a.z;
      As[(lak + 3) * 128 + lam] = a.w;
    }
    {
      int kk = k0 + kb + lbk;
      int row = (kk & 2047) * 49 + (kk >> 11);  // pooled col s*2048+c  ->  w row c*49+s
      float4 b = *(const float4*)&w[(size_t)row * 1024 + n0 + lbn];
      *(float4*)&Bs[lbk * 132 + lbn] = b;
    }
    __syncthreads();
#pragma unroll
    for (int k = 0; k < 8; ++k) {
      float a[8], bb[8];
      *(float4*)&a[0] = *(const float4*)&As[k * 128 + tm * 8];
      *(float4*)&a[4] = *(const float4*)&As[k * 128 + tm * 8 + 4];
      *(float4*)&bb[0] = *(const float4*)&Bs[k * 132 + tn * 8];
      *(float4*)&bb[4] = *(const float4*)&Bs[k * 132 + tn * 8 + 4];
#pragma unroll
      for (int i = 0; i < 8; ++i)
#pragma unroll
        for (int j = 0; j < 8; ++j) acc[i][j] += a[i] * bb[j];
    }
    __syncthreads();
  }
#pragma unroll
  for (int i = 0; i < 8; ++i)
#pragma unroll
    for (int j = 0; j < 8; ++j)
      part[((size_t)ks * 256 + m0 + tm * 8 + i) * 1024 + n0 + tn * 8 + j] = acc[i][j];
}

__launch_bounds__(256)
__global__ void fc1_reduce_k(const float* __restrict__ part, const float* __restrict__ bias,
                             float* __restrict__ h1) {
  int idx = blockIdx.x * 256 + threadIdx.x;  // < 262144
  int n = idx & 1023;
  float v = bias[n];
#pragma unroll
  for (int ks = 0; ks < 16; ++ks) v += part[(size_t)ks * 262144 + idx];
  h1[idx] = v;  // relu applied on load in fc2
}

// ---------------- fc2: relu(h1) @ [1024,1024] + b ----------------
__launch_bounds__(256)
__global__ void fc2_k(const float* __restrict__ h1, const float* __restrict__ w,
                      const float* __restrict__ b, float* __restrict__ h2) {
  __shared__ float hs[1024];
  int r = blockIdx.x;
  int tid = threadIdx.x;
  for (int k = tid; k < 1024; k += 256) hs[k] = fmaxf(h1[(size_t)r * 1024 + k], 0.f);
  __syncthreads();
  float acc0 = 0.f, acc1 = 0.f, acc2 = 0.f, acc3 = 0.f;
#pragma unroll 4
  for (int k = 0; k < 1024; ++k) {
    float hv = hs[k];
    const float* wr = w + (size_t)k * 1024;
    acc0 += hv * wr[tid];
    acc1 += hv * wr[tid + 256];
    acc2 += hv * wr[tid + 512];
    acc3 += hv * wr[tid + 768];
  }
  h2[(size_t)r * 1024 + tid] = acc0 + b[tid];
  h2[(size_t)r * 1024 + tid + 256] = acc1 + b[tid + 256];
  h2[(size_t)r * 1024 + tid + 512] = acc2 + b[tid + 512];
  h2[(size_t)r * 1024 + tid + 768] = acc3 + b[tid + 768];
}

// ---------------- heads: relu(h2) @ cls/box, concat -> out[256,455] ----------------
__launch_bounds__(256)
__global__ void head_k(const float* __restrict__ h2, const float* __restrict__ cls_w,
                       const float* __restrict__ cls_b, const float* __restrict__ box_w,
                       const float* __restrict__ box_b, float* __restrict__ out) {
  __shared__ float hs[1024];
  int r = blockIdx.x;
  int tid = threadIdx.x;
  for (int k = tid; k < 1024; k += 256) hs[k] = fmaxf(h2[(size_t)r * 1024 + k], 0.f);
  __syncthreads();
  for (int n = tid; n < 455; n += 256) {
    float acc = 0.f;
    if (n < 91) {
#pragma unroll 4
      for (int k = 0; k < 1024; ++k) acc += hs[k] * cls_w[(size_t)k * 91 + n];
      acc += cls_b[n];
    } else {
      int nb = n - 91;
#pragma unroll 4
      for (int k = 0; k < 1024; ++k) acc += hs[k] * box_w[(size_t)k * 364 + nb];
      acc += box_b[nb];
    }
    out[(size_t)r * 455 + n] = acc;
  }
}

// ---------------- launcher ----------------
extern "C" void kernel_launch(void* const* d_in, const int* in_sizes, int n_in, void* d_out,
                              int out_size, void* d_ws, size_t ws_size, hipStream_t stream) {
  const float* img    = (const float*)d_in[0];
  const float* w_stem = (const float*)d_in[1];
  const float* w1     = (const float*)d_in[2];
  const float* w2     = (const float*)d_in[3];
  const float* w3     = (const float*)d_in[4];
  const float* w4     = (const float*)d_in[5];
  const float* w_rpn  = (const float*)d_in[6];
  const float* b_rpn  = (const float*)d_in[7];
  const float* w_obj  = (const float*)d_in[8];
  const float* b_obj  = (const float*)d_in[9];
  const float* w_reg  = (const float*)d_in[10];
  const float* b_regc = (const float*)d_in[11];
  const float* fc1_w  = (const float*)d_in[12];
  const float* fc1_b  = (const float*)d_in[13];
  const float* fc2_w  = (const float*)d_in[14];
  const float* fc2_b  = (const float*)d_in[15];
  const float* cls_w  = (const float*)d_in[16];
  const float* cls_b  = (const float*)d_in[17];
  const float* box_w  = (const float*)d_in[18];
  const float* box_b  = (const float*)d_in[19];
  float* W = (float*)d_ws;
  float* out = (float*)d_out;

  stem_k<<<64 * 256, 256, 0, stream>>>(img, w_stem, W + BIGA);
  maxpool_k<<<4096, 256, 0, stream>>>(W + BIGA, W + BIGB);
  conv3_k<1, 64, 256, 4, 4, 128, 128, 1, false, true>
      <<<1024, 128, 0, stream>>>(W + BIGB, w1, nullptr, W + BIGA);
  // c2: stride-2 direct-global, KSPLIT=4 -> partials, combine+relu -> BIGB
  conv3s2_k<256, 512, 128, 128, 4><<<1024, 256, 0, stream>>>(W + BIGA, w2, W + PARTO);
  combN_k<4, 2097152, false><<<8192, 256, 0, stream>>>(W + PARTO, nullptr, W + BIGB);
  // c3: stride-2 direct-global, KSPLIT=8 -> partials, combine+relu -> BIGC
  conv3s2_k<512, 1024, 64, 64, 8><<<1024, 256, 0, stream>>>(W + BIGB, w3, W + PARTO);
  combN_k<8, 1048576, false><<<4096, 256, 0, stream>>>(W + PARTO, nullptr, W + BIGC);
  // c4: KSPLIT=8 (was 4) for occupancy
  conv3_k<1, 1024, 2048, 8, 4, 32, 32, 8, false, false>
      <<<2048, 128, 0, stream>>>(W + BIGC, w4, nullptr, W + PARTO);
  combN_k<8, 2097152, false><<<8192, 256, 0, stream>>>(W + PARTO, nullptr, W + FEATO);
  transpose_k<<<2048, 256, 0, stream>>>(W + FEATO, W + FEATT);
  // rpn: KSPLIT=8 (was 4)
  conv3_k<1, 2048, 2048, 8, 4, 32, 32, 8, false, false>
      <<<2048, 128, 0, stream>>>(W + FEATO, w_rpn, nullptr, W + PARTO);
  combN_k<8, 2097152, true><<<8192, 256, 0, stream>>>(W + PARTO, b_rpn, W + BIGB);  // T = BIGB
  conv1x1_k<<<12 * 4, 256, 0, stream>>>(W + BIGB, w_obj, b_obj, W + OBJO);
  conv1x1_k<<<48 * 4, 256, 0, stream>>>(W + BIGB, w_reg, b_regc, W + REGO);
  decode_k<<<48, 256, 0, stream>>>(W + OBJO, W + REGO, W + BOXO,
                                   (unsigned long long*)(W + KEYO));
  topk_k<<<48, 256, 0, stream>>>((const unsigned long long*)(W + KEYO), W + BOXO, W + CANDO);
  iou_sup_k<<<1000, 64, 0, stream>>>(W + CANDO, (unsigned long long*)(W + SUPO));
  nms_k<<<1, 64, 0, stream>>>(W + CANDO, (const unsigned long long*)(W + SUPO), W + PROPO);
  roi_pool_k<<<256 * 49, 256, 0, stream>>>(W + FEATT, W + PROPO, W + POOLO);
  fc1_gemm_k<<<256, 256, 0, stream>>>(W + POOLO, fc1_w, W + FC1PO);
  fc1_reduce_k<<<1024, 256, 0, stream>>>(W + FC1PO, fc1_b, W + H1O);
  fc2_k<<<256, 256, 0, stream>>>(W + H1O, fc2_w, fc2_b, W + H2O);
  head_k<<<256, 256, 0, stream>>>(W + H2O, cls_w, cls_b, box_w, box_b, out);
}